// Round 8
// baseline (343.289 us; speedup 1.0000x reference)
//
#include <hip/hip_runtime.h>
#include <hip/hip_bf16.h>
#include <stdint.h>

typedef unsigned short u16;
typedef unsigned int u32;

#define T_TOK 8192
#define DIN   4096
#define DOUT  4096
#define NL    16
#define NR    16
#define KX    4096              // x part of extended-K
#define K2    4416              // physical row stride (cols 4352+ unused now)
#define NKT   68                // K-tiles of 64 actually computed (bias via epilogue)
#define GITERS 34               // 2 K-tiles per iter, exact

typedef __attribute__((ext_vector_type(8))) __bf16 bf16x8;
typedef __attribute__((ext_vector_type(4))) float  f32x4;

__device__ __forceinline__ u32 bf16rne(float f) {
    u32 x = __float_as_uint(f);
    return (x + 0x7FFFu + ((x >> 16) & 1u)) >> 16;
}
__device__ __forceinline__ u32 pack2(float a, float b) {
    return bf16rne(a) | (bf16rne(b) << 16);
}

// ---------------- pack_all: x->A', W->B', lora_b->B' extra cols, lora_a->bf16 ------
#define NCHUNK_XW ((T_TOK + DOUT) * 512)
#define NCHUNK_BX (DOUT * 32)           // 256 Z-cols / 8 per output row
#define NCHUNK_LA (NL * NR * DIN / 8)
__global__ void pack_all(const float* __restrict__ x, const float* __restrict__ W,
                         const float* __restrict__ lora_b, const float* __restrict__ la,
                         u16* __restrict__ Abf, u16* __restrict__ Bbf,
                         u16* __restrict__ Aabf) {
    const int total = NCHUNK_XW + NCHUNK_BX + NCHUNK_LA;
    for (int i = blockIdx.x * blockDim.x + threadIdx.x; i < total;
         i += gridDim.x * blockDim.x) {
        const float* s;
        u16* d;
        if (i < NCHUNK_XW) {
            int row = i >> 9;
            int c8  = (i & 511) << 3;
            if (row < T_TOK) { s = x + (size_t)row * DIN + c8; d = Abf + (size_t)row * K2 + c8; }
            else { s = W + (size_t)(row - T_TOK) * DIN + c8; d = Bbf + (size_t)(row - T_TOK) * K2 + c8; }
        } else if (i < NCHUNK_XW + NCHUNK_BX) {
            int j = i - NCHUNK_XW;
            int o = j >> 5;
            int c8 = (j & 31) << 3;             // Z-col base 0..248
            int l = c8 >> 4, rb = c8 & 15;      // 8 consecutive r within one l
            s = lora_b + ((size_t)l * DOUT + o) * NR + rb;
            d = Bbf + (size_t)o * K2 + KX + c8;
        } else {
            int c8 = (i - NCHUNK_XW - NCHUNK_BX) << 3;
            s = la + c8;
            d = Aabf + c8;
        }
        const float4* s4 = (const float4*)s;
        float4 f0 = s4[0], f1 = s4[1];
        uint4 u;
        u.x = pack2(f0.x, f0.y); u.y = pack2(f0.z, f0.w);
        u.z = pack2(f1.x, f1.y); u.w = pack2(f1.z, f1.w);
        *(uint4*)d = u;
    }
}

// ---------------- zfill: Z = masked(x_bf16 @ lora_a^T), 2 blocks/CU ----------------
// grid 512 = 128 token-groups(64) x 4 col-quarters(64); 256 thr = 4 waves (2M x 2N).
__global__ __launch_bounds__(256) void zfill_kernel(const u16* __restrict__ Axr,
                                                    const u16* __restrict__ La,
                                                    const int* __restrict__ idx,
                                                    u16* __restrict__ Abf) {
    __shared__ u16 sX[2][64 * 64];        // 8KB each
    __shared__ u16 sL[2][64 * 64];        // 8KB each
    const int tid  = threadIdx.x;
    const int lane = tid & 63, wid = tid >> 6;
    const int wr = wid >> 1, wc = wid & 1;
    const int lrow = lane & 15;
    const int klo  = (lane >> 4) << 4;
    const int sxr  = (lrow & 7) << 4;
    const int kxb[2] = { klo ^ sxr, (64 + klo) ^ sxr };

    const int bt = blockIdx.x >> 2;       // token group (64 tokens)
    const int nh = blockIdx.x & 3;        // col quarter (64 Z-cols)

    const int r0 = tid >> 3;              // 0..31
    const int c4 = (tid & 7) ^ (r0 & 7);  // pre-swizzled source chunk
    const u16* pX = Axr + (size_t)(bt * 64 + r0) * K2 + c4 * 8;
    const u16* pL = La + (size_t)(nh * 64 + r0) * DIN + c4 * 8;

    f32x4 acc[2][2];
#pragma unroll
    for (int m = 0; m < 2; ++m)
#pragma unroll
        for (int n = 0; n < 2; ++n) { f32x4 z = {0.f,0.f,0.f,0.f}; acc[m][n] = z; }

#define STAGEZ(buf, kt)                                                                 \
  do {                                                                                  \
    __builtin_amdgcn_global_load_lds(                                                   \
      (const __attribute__((address_space(1))) u32*)(pX + (size_t)(kt) * 64),           \
      (__attribute__((address_space(3))) u32*)(&sX[buf][tid * 8]), 16, 0, 0);           \
    __builtin_amdgcn_global_load_lds(                                                   \
      (const __attribute__((address_space(1))) u32*)(pX + (size_t)32 * K2 + (size_t)(kt) * 64),  \
      (__attribute__((address_space(3))) u32*)(&sX[buf][2048 + tid * 8]), 16, 0, 0);    \
    __builtin_amdgcn_global_load_lds(                                                   \
      (const __attribute__((address_space(1))) u32*)(pL + (size_t)(kt) * 64),           \
      (__attribute__((address_space(3))) u32*)(&sL[buf][tid * 8]), 16, 0, 0);           \
    __builtin_amdgcn_global_load_lds(                                                   \
      (const __attribute__((address_space(1))) u32*)(pL + (size_t)32 * DIN + (size_t)(kt) * 64), \
      (__attribute__((address_space(3))) u32*)(&sL[buf][2048 + tid * 8]), 16, 0, 0);    \
  } while (0)

    STAGEZ(0, 0);
    for (int kt = 0; kt < 64; ++kt) {
        const int cur = kt & 1;
        if (kt < 63) {
            STAGEZ(cur ^ 1, kt + 1);
            asm volatile("s_waitcnt vmcnt(4)" ::: "memory");
        } else {
            asm volatile("s_waitcnt vmcnt(0)" ::: "memory");
        }
        __builtin_amdgcn_sched_barrier(0);
        __builtin_amdgcn_s_barrier();
        __builtin_amdgcn_sched_barrier(0);
        const char* sx = (const char*)sX[cur];
        const char* sl = (const char*)sL[cur];
        bf16x8 a[2][2], b[2][2];
#pragma unroll
        for (int m = 0; m < 2; ++m)
#pragma unroll
            for (int kk = 0; kk < 2; ++kk)
                a[m][kk] = *(const bf16x8*)(sx + (wr * 32 + m * 16 + lrow) * 128 + kxb[kk]);
#pragma unroll
        for (int n = 0; n < 2; ++n)
#pragma unroll
            for (int kk = 0; kk < 2; ++kk)
                b[n][kk] = *(const bf16x8*)(sl + (wc * 32 + n * 16 + lrow) * 128 + kxb[kk]);
#pragma unroll
        for (int m = 0; m < 2; ++m)
#pragma unroll
            for (int n = 0; n < 2; ++n)
#pragma unroll
                for (int kk = 0; kk < 2; ++kk)
                    acc[m][n] = __builtin_amdgcn_mfma_f32_16x16x32_bf16(
                        a[m][kk], b[n][kk], acc[m][n], 0, 0, 0);
        __builtin_amdgcn_sched_barrier(0);
        __builtin_amdgcn_s_barrier();
        __builtin_amdgcn_sched_barrier(0);
    }

    // masked Z write: Z[t][col] = (idx[t] == col>>4) ? Zfull : 0
#pragma unroll
    for (int m = 0; m < 2; ++m) {
#pragma unroll
        for (int rg = 0; rg < 4; ++rg) {
            int t = bt * 64 + wr * 32 + m * 16 + ((lane >> 4) << 2) + rg;
            int l = idx[t];
#pragma unroll
            for (int n = 0; n < 2; ++n) {
                int colr = nh * 64 + wc * 32 + n * 16 + (lane & 15);
                u16 v = ((colr >> 4) == l) ? (u16)bf16rne(acc[m][n][rg]) : (u16)0;
                Abf[(size_t)t * K2 + KX + colr] = v;
            }
        }
    }
}

// ---------------- main GEMM: r6 structure (4-phase, 1 barrier/phase) + bias epilogue --
#define SBAR() __builtin_amdgcn_sched_barrier(0)
#define HWBAR() __builtin_amdgcn_s_barrier()
#define PHASE_BAR() do { SBAR(); HWBAR(); SBAR(); } while (0)
#define VMCNT4() asm volatile("s_waitcnt vmcnt(4)" ::: "memory")
#define VMCNT0() asm volatile("s_waitcnt vmcnt(0)" ::: "memory")

#define STAGE(ptr, h, buf, seg, kt)                                                   \
  do { if ((kt) < NKT) {                                                              \
    __builtin_amdgcn_global_load_lds(                                                 \
      (const __attribute__((address_space(1))) u32*)((ptr) + (size_t)((h)*128 + 0)*K2 + (size_t)(kt)*64),  \
      (__attribute__((address_space(3))) u32*)(lds16 + ((((buf)*4+(seg))<<13) + tid*8)), 16, 0, 0);        \
    __builtin_amdgcn_global_load_lds(                                                 \
      (const __attribute__((address_space(1))) u32*)((ptr) + (size_t)((h)*128 + 64)*K2 + (size_t)(kt)*64), \
      (__attribute__((address_space(3))) u32*)(lds16 + ((((buf)*4+(seg))<<13) + tid*8 + 4096)), 16, 0, 0); \
  } } while (0)

#define RD_AH(buf, mh, aa)                                                            \
  { _Pragma("unroll") for (int mm = 0; mm < 4; ++mm)                                  \
    _Pragma("unroll") for (int kk = 0; kk < 2; ++kk)                                  \
      aa[mm][kk] = *(const bf16x8*)(smem + (((buf)*4 + wr) << 14) + lrow*128          \
          + (mh)*8192 + mm*2048 + kxb[kk]); }

#define RD_BH(buf, nh, bf)                                                            \
  { _Pragma("unroll") for (int nn = 0; nn < 2; ++nn)                                  \
    _Pragma("unroll") for (int kk = 0; kk < 2; ++kk)                                  \
      bf[nn][kk] = *(const bf16x8*)(smem + (((buf)*4 + 2 + (wc>>1)) << 14)            \
          + ((wc&1)*64 + lrow)*128 + ((nh)*2+nn)*2048 + kxb[kk]); }

#define MMQ(mh, nh, aa, bf)                                                           \
  { __builtin_amdgcn_s_setprio(1);                                                    \
    _Pragma("unroll") for (int mm = 0; mm < 4; ++mm)                                  \
    _Pragma("unroll") for (int nn = 0; nn < 2; ++nn)                                  \
    _Pragma("unroll") for (int kk = 0; kk < 2; ++kk)                                  \
      acc[(mh)*4+mm][(nh)*2+nn] = __builtin_amdgcn_mfma_f32_16x16x32_bf16(            \
          aa[mm][kk], bf[nn][kk], acc[(mh)*4+mm][(nh)*2+nn], 0, 0, 0);                \
    __builtin_amdgcn_s_setprio(0); }

__global__ __launch_bounds__(512, 2) void gemm_kernel(const u16* __restrict__ A,
                                                      const u16* __restrict__ B,
                                                      const float* __restrict__ base_bias,
                                                      const float* __restrict__ bias_st,
                                                      const int* __restrict__ gidx,
                                                      float* __restrict__ C) {
    __shared__ u16 lds16[65536];                 // 128 KiB
    const char* smem = (const char*)lds16;

    const int tid  = threadIdx.x;
    const int lane = tid & 63, wid = tid >> 6;
    const int wr = wid >> 2, wc = wid & 3;       // 2M x 4N wave grid
    const int lrow = lane & 15;
    const int klo  = (lane >> 4) << 4;
    const int sx   = (lrow & 7) << 4;
    const int kxb[2] = { klo ^ sx, (64 + klo) ^ sx };

    // XCD-aware swizzle: 512 blocks, 512 % 8 == 0 -> bijective
    const int wg  = blockIdx.x;
    const int swz = (wg & 7) * 64 + (wg >> 3);
    const int bm = swz >> 4;                     // 32 row-tiles
    const int bn = swz & 15;                     // 16 col-tiles

    const int r0  = tid >> 3;
    const int sc4 = (tid & 7) ^ (r0 & 7);
    const u16* pA = A + (size_t)(bm * 256 + r0) * K2 + sc4 * 8;
    const u16* pB = B + (size_t)(bn * 256 + r0) * K2 + sc4 * 8;

    f32x4 acc[8][4];
#pragma unroll
    for (int m = 0; m < 8; ++m)
#pragma unroll
        for (int n = 0; n < 4; ++n) { f32x4 z = {0.f,0.f,0.f,0.f}; acc[m][n] = z; }
    bf16x8 a0[4][2], a1[4][2], bA[2][2], bB[2][2];

    // prologue: K0 all 4 segs (b0) + K1 A0,B0 (b1 segs 0,2); K1 A1,B1 at ph1
    STAGE(pA, 0, 0, 0, 0); STAGE(pA, 1, 0, 1, 0);
    STAGE(pB, 0, 0, 2, 0); STAGE(pB, 1, 0, 3, 0);
    STAGE(pA, 0, 1, 0, 1); STAGE(pB, 0, 1, 2, 1);
    VMCNT4();                                    // 12 out -> K0's 8 landed
    PHASE_BAR();

    for (int i = 0; i < GITERS; ++i) {
        const int kO = 2 * i + 1, kE2 = 2 * i + 2, kO2 = 2 * i + 3;
        // ph1: E=2i mh0; stage O.A1->b1.s1, O.B1->b1.s3
        RD_AH(0, 0, a0); RD_BH(0, 0, bA); RD_BH(0, 1, bB);
        STAGE(pA, 1, 1, 1, kO); STAGE(pB, 1, 1, 3, kO);
        MMQ(0, 0, a0, bA); MMQ(0, 1, a0, bB);
        PHASE_BAR();
        // ph2: E mh1; stage E'.A0->b0.s0, E'.B0->b0.s2; guard O landed.
        // Last iter: ph2 staged nothing (kE2=68 clipped) -> steady vmcnt(4)
        // would leave O's A1/B1 in flight; drain fully instead.
        RD_AH(0, 1, a1);
        STAGE(pA, 0, 0, 0, kE2); STAGE(pB, 0, 0, 2, kE2);
        MMQ(1, 0, a1, bA); MMQ(1, 1, a1, bB);
        if (i == GITERS - 1) { VMCNT0(); } else { VMCNT4(); }
        PHASE_BAR();
        // ph3: O mh0; stage E'.A1->b0.s1, E'.B1->b0.s3
        RD_AH(1, 0, a0); RD_BH(1, 0, bA); RD_BH(1, 1, bB);
        STAGE(pA, 1, 0, 1, kE2); STAGE(pB, 1, 0, 3, kE2);
        MMQ(0, 0, a0, bA); MMQ(0, 1, a0, bB);
        PHASE_BAR();
        // ph4: O mh1; stage O'.A0->b1.s0, O'.B0->b1.s2; guard E' landed
        RD_AH(1, 1, a1);
        STAGE(pA, 0, 1, 0, kO2); STAGE(pB, 0, 1, 2, kO2);
        MMQ(1, 0, a1, bA); MMQ(1, 1, a1, bB);
        VMCNT4();
        PHASE_BAR();
    }

    // epilogue: C/D layout col = lane&15, row = (lane>>4)*4 + reg; bias fused f32
    const int crow0 = bm * 256 + wr * 128 + ((lane >> 4) << 2);
    const int ccol0 = bn * 256 + wc * 64 + (lane & 15);
    float bb[4];
#pragma unroll
    for (int n = 0; n < 4; ++n) bb[n] = base_bias[ccol0 + n * 16];
#pragma unroll
    for (int m = 0; m < 8; ++m) {
#pragma unroll
        for (int rg = 0; rg < 4; ++rg) {
            int row = crow0 + m * 16 + rg;
            int l = gidx[row];
#pragma unroll
            for (int n = 0; n < 4; ++n) {
                float v = acc[m][n][rg] + bb[n];
                if (l >= 0) v += bias_st[(size_t)l * DOUT + ccol0 + n * 16];
                C[(size_t)row * DOUT + ccol0 + n * 16] = v;
            }
        }
    }
}

// ---------------- launch ----------------

extern "C" void kernel_launch(void* const* d_in, const int* in_sizes, int n_in,
                              void* d_out, int out_size, void* d_ws, size_t ws_size,
                              hipStream_t stream) {
    const float* x         = (const float*)d_in[0];
    const float* W         = (const float*)d_in[1];
    const float* base_bias = (const float*)d_in[2];
    const float* lora_a    = (const float*)d_in[3];
    const float* lora_b    = (const float*)d_in[4];
    const float* bias_st   = (const float*)d_in[5];
    const int*   indices   = (const int*)d_in[6];
    float* out = (float*)d_out;

    u16* Abf  = (u16*)d_ws;                         // [T_TOK][K2] bf16
    u16* Bbf  = Abf + (size_t)T_TOK * K2;           // [DOUT][K2] bf16
    u16* Aabf = Bbf + (size_t)DOUT * K2;            // [256][DIN] bf16 lora_a

    pack_all<<<6144, 256, 0, stream>>>(x, W, lora_b, lora_a, Abf, Bbf, Aabf);
    zfill_kernel<<<512, 256, 0, stream>>>(Abf, Aabf, indices, Abf);
    gemm_kernel<<<512, 512, 0, stream>>>(Abf, Bbf, base_bias, bias_st, indices, out);
    (void)in_sizes; (void)n_in; (void)out_size; (void)ws_size;
}

// Round 9
// 323.984 us; speedup vs baseline: 1.0596x; 1.0596x over previous
//
#include <hip/hip_runtime.h>
#include <hip/hip_bf16.h>
#include <stdint.h>

typedef unsigned short u16;
typedef unsigned int u32;

#define T_TOK 8192
#define DIN   4096
#define DOUT  4096
#define NL    16
#define NR    16
#define KX    4096              // x part of extended-K
#define K2    4416              // 4096 + 256 (Z) + 64 (bias/onehot/pad) = 69*64
#define NKT   69                // K-tiles of 64
#define GITERS 34               // 2 K-tiles per iter; K-tile 68 in tail

typedef __attribute__((ext_vector_type(8))) __bf16 bf16x8;
typedef __attribute__((ext_vector_type(4))) float  f32x4;

__device__ __forceinline__ u32 bf16rne(float f) {
    u32 x = __float_as_uint(f);
    return (x + 0x7FFFu + ((x >> 16) & 1u)) >> 16;
}
__device__ __forceinline__ u32 pack2(float a, float b) {
    return bf16rne(a) | (bf16rne(b) << 16);
}

// ---------------- pack_all: x->A', W->B' (+Z cols, +bias cols), lora_a->bf16 ------
#define NCHUNK_XW ((T_TOK + DOUT) * 512)
#define NCHUNK_BZ (DOUT * 32)           // 256 Z-cols / 8 per output row
#define NCHUNK_BB (DOUT * 8)            // 64 bias/onehot cols / 8 per output row
#define NCHUNK_LA (NL * NR * DIN / 8)
__global__ void pack_all(const float* __restrict__ x, const float* __restrict__ W,
                         const float* __restrict__ lora_b,
                         const float* __restrict__ base_bias,
                         const float* __restrict__ bias_st,
                         const float* __restrict__ la,
                         u16* __restrict__ Abf, u16* __restrict__ Bbf,
                         u16* __restrict__ Aabf) {
    const int total = NCHUNK_XW + NCHUNK_BZ + NCHUNK_BB + NCHUNK_LA;
    for (int i = blockIdx.x * blockDim.x + threadIdx.x; i < total;
         i += gridDim.x * blockDim.x) {
        if (i < NCHUNK_XW + NCHUNK_BZ) {
            const float* s;
            u16* d;
            if (i < NCHUNK_XW) {
                int row = i >> 9;
                int c8  = (i & 511) << 3;
                if (row < T_TOK) { s = x + (size_t)row * DIN + c8; d = Abf + (size_t)row * K2 + c8; }
                else { s = W + (size_t)(row - T_TOK) * DIN + c8; d = Bbf + (size_t)(row - T_TOK) * K2 + c8; }
            } else {
                int j = i - NCHUNK_XW;
                int o = j >> 5;
                int c8 = (j & 31) << 3;             // Z-col base 0..248
                int l = c8 >> 4, rb = c8 & 15;      // 8 consecutive r within one l
                s = lora_b + ((size_t)l * DOUT + o) * NR + rb;
                d = Bbf + (size_t)o * K2 + KX + c8;
            }
            const float4* s4 = (const float4*)s;
            float4 f0 = s4[0], f1 = s4[1];
            uint4 u;
            u.x = pack2(f0.x, f0.y); u.y = pack2(f0.z, f0.w);
            u.z = pack2(f1.x, f1.y); u.w = pack2(f1.z, f1.w);
            *(uint4*)d = u;
        } else if (i < NCHUNK_XW + NCHUNK_BZ + NCHUNK_BB) {
            int j = i - NCHUNK_XW - NCHUNK_BZ;
            int o = j >> 3;
            int c8 = (j & 7) << 3;                  // 0..56 within the 64 bias cols
            u32 w[4];
#pragma unroll
            for (int q = 0; q < 4; ++q) {
                float v0 = 0.f, v1 = 0.f;
                int e0 = c8 + 2 * q;                // 0..63
                if (e0 == 0) v0 = base_bias[o];
                else if (e0 <= 16) v0 = bias_st[(size_t)(e0 - 1) * DOUT + o];
                int e1 = e0 + 1;
                if (e1 <= 16) v1 = bias_st[(size_t)(e1 - 1) * DOUT + o];
                w[q] = pack2(v0, v1);
            }
            *(uint4*)(Bbf + (size_t)o * K2 + KX + 256 + c8) = *(uint4*)w;
        } else {
            int c8 = (i - NCHUNK_XW - NCHUNK_BZ - NCHUNK_BB) << 3;
            const float4* s4 = (const float4*)(la + c8);
            float4 f0 = s4[0], f1 = s4[1];
            uint4 u;
            u.x = pack2(f0.x, f0.y); u.y = pack2(f0.z, f0.w);
            u.z = pack2(f1.x, f1.y); u.w = pack2(f1.z, f1.w);
            *(uint4*)(Aabf + c8) = u;
        }
    }
}

// ---------------- zfill: Z = masked(x_bf16 @ lora_a^T), 2 blocks/CU ----------------
// grid 512 = 128 token-groups(64) x 4 col-quarters(64); 256 thr = 4 waves (2M x 2N).
// nh==0 blocks also write the bias/onehot cols 4352..4415 for their tokens.
__global__ __launch_bounds__(256) void zfill_kernel(const u16* __restrict__ Axr,
                                                    const u16* __restrict__ La,
                                                    const int* __restrict__ idx,
                                                    u16* __restrict__ Abf) {
    __shared__ u16 sX[2][64 * 64];        // 8KB each
    __shared__ u16 sL[2][64 * 64];        // 8KB each
    const int tid  = threadIdx.x;
    const int lane = tid & 63, wid = tid >> 6;
    const int wr = wid >> 1, wc = wid & 1;
    const int lrow = lane & 15;
    const int klo  = (lane >> 4) << 4;
    const int sxr  = (lrow & 7) << 4;
    const int kxb[2] = { klo ^ sxr, (64 + klo) ^ sxr };

    const int bt = blockIdx.x >> 2;       // token group (64 tokens)
    const int nh = blockIdx.x & 3;        // col quarter (64 Z-cols)

    const int r0 = tid >> 3;              // 0..31
    const int c4 = (tid & 7) ^ (r0 & 7);  // pre-swizzled source chunk
    const u16* pX = Axr + (size_t)(bt * 64 + r0) * K2 + c4 * 8;
    const u16* pL = La + (size_t)(nh * 64 + r0) * DIN + c4 * 8;

    f32x4 acc[2][2];
#pragma unroll
    for (int m = 0; m < 2; ++m)
#pragma unroll
        for (int n = 0; n < 2; ++n) { f32x4 z = {0.f,0.f,0.f,0.f}; acc[m][n] = z; }

#define STAGEZ(buf, kt)                                                                 \
  do {                                                                                  \
    __builtin_amdgcn_global_load_lds(                                                   \
      (const __attribute__((address_space(1))) u32*)(pX + (size_t)(kt) * 64),           \
      (__attribute__((address_space(3))) u32*)(&sX[buf][tid * 8]), 16, 0, 0);           \
    __builtin_amdgcn_global_load_lds(                                                   \
      (const __attribute__((address_space(1))) u32*)(pX + (size_t)32 * K2 + (size_t)(kt) * 64),  \
      (__attribute__((address_space(3))) u32*)(&sX[buf][2048 + tid * 8]), 16, 0, 0);    \
    __builtin_amdgcn_global_load_lds(                                                   \
      (const __attribute__((address_space(1))) u32*)(pL + (size_t)(kt) * 64),           \
      (__attribute__((address_space(3))) u32*)(&sL[buf][tid * 8]), 16, 0, 0);           \
    __builtin_amdgcn_global_load_lds(                                                   \
      (const __attribute__((address_space(1))) u32*)(pL + (size_t)32 * DIN + (size_t)(kt) * 64), \
      (__attribute__((address_space(3))) u32*)(&sL[buf][2048 + tid * 8]), 16, 0, 0);    \
  } while (0)

    STAGEZ(0, 0);
    for (int kt = 0; kt < 64; ++kt) {
        const int cur = kt & 1;
        if (kt < 63) {
            STAGEZ(cur ^ 1, kt + 1);
            asm volatile("s_waitcnt vmcnt(4)" ::: "memory");
        } else {
            asm volatile("s_waitcnt vmcnt(0)" ::: "memory");
        }
        __builtin_amdgcn_sched_barrier(0);
        __builtin_amdgcn_s_barrier();
        __builtin_amdgcn_sched_barrier(0);
        const char* sx = (const char*)sX[cur];
        const char* sl = (const char*)sL[cur];
        bf16x8 a[2][2], b[2][2];
#pragma unroll
        for (int m = 0; m < 2; ++m)
#pragma unroll
            for (int kk = 0; kk < 2; ++kk)
                a[m][kk] = *(const bf16x8*)(sx + (wr * 32 + m * 16 + lrow) * 128 + kxb[kk]);
#pragma unroll
        for (int n = 0; n < 2; ++n)
#pragma unroll
            for (int kk = 0; kk < 2; ++kk)
                b[n][kk] = *(const bf16x8*)(sl + (wc * 32 + n * 16 + lrow) * 128 + kxb[kk]);
#pragma unroll
        for (int m = 0; m < 2; ++m)
#pragma unroll
            for (int n = 0; n < 2; ++n)
#pragma unroll
                for (int kk = 0; kk < 2; ++kk)
                    acc[m][n] = __builtin_amdgcn_mfma_f32_16x16x32_bf16(
                        a[m][kk], b[n][kk], acc[m][n], 0, 0, 0);
        __builtin_amdgcn_sched_barrier(0);
        __builtin_amdgcn_s_barrier();
        __builtin_amdgcn_sched_barrier(0);
    }

    // masked Z write: Z[t][col] = (idx[t] == col>>4) ? Zfull : 0
#pragma unroll
    for (int m = 0; m < 2; ++m) {
#pragma unroll
        for (int rg = 0; rg < 4; ++rg) {
            int t = bt * 64 + wr * 32 + m * 16 + ((lane >> 4) << 2) + rg;
            int l = idx[t];
#pragma unroll
            for (int n = 0; n < 2; ++n) {
                int colr = nh * 64 + wc * 32 + n * 16 + (lane & 15);
                u16 v = ((colr >> 4) == l) ? (u16)bf16rne(acc[m][n][rg]) : (u16)0;
                Abf[(size_t)t * K2 + KX + colr] = v;
            }
        }
    }
    // bias/onehot cols 4352..4415: col 4352 = 1.0 always; 4353+l = 1.0 if l>=0
    if (nh == 0) {
        int tl = tid >> 2;                 // token 0..63
        int q4 = tid & 3;                  // 16-col quarter
        int t = bt * 64 + tl;
        int l = idx[t];
        u32 w[8];
#pragma unroll
        for (int q = 0; q < 8; ++q) {
            int e0 = q4 * 16 + 2 * q;      // 0..63 within bias region
            u32 v0 = (e0 == 0 || (l >= 0 && e0 == 1 + l)) ? 0x3F80u : 0u;
            int e1 = e0 + 1;
            u32 v1 = (e1 == 0 || (l >= 0 && e1 == 1 + l)) ? 0x3F80u : 0u;
            w[q] = v0 | (v1 << 16);
        }
        u16* dst = Abf + (size_t)t * K2 + KX + 256 + q4 * 16;
        *(uint4*)dst = *(uint4*)&w[0];
        *(uint4*)(dst + 8) = *(uint4*)&w[4];
    }
}

// ---------------- main GEMM: r6-exact (4-phase, 1 barrier/phase, K-tile bias) --------
#define SBAR() __builtin_amdgcn_sched_barrier(0)
#define HWBAR() __builtin_amdgcn_s_barrier()
#define PHASE_BAR() do { SBAR(); HWBAR(); SBAR(); } while (0)
#define VMCNT4() asm volatile("s_waitcnt vmcnt(4)" ::: "memory")
#define VMCNT0() asm volatile("s_waitcnt vmcnt(0)" ::: "memory")

#define STAGE(ptr, h, buf, seg, kt)                                                   \
  do { if ((kt) < NKT) {                                                              \
    __builtin_amdgcn_global_load_lds(                                                 \
      (const __attribute__((address_space(1))) u32*)((ptr) + (size_t)((h)*128 + 0)*K2 + (size_t)(kt)*64),  \
      (__attribute__((address_space(3))) u32*)(lds16 + ((((buf)*4+(seg))<<13) + tid*8)), 16, 0, 0);        \
    __builtin_amdgcn_global_load_lds(                                                 \
      (const __attribute__((address_space(1))) u32*)((ptr) + (size_t)((h)*128 + 64)*K2 + (size_t)(kt)*64), \
      (__attribute__((address_space(3))) u32*)(lds16 + ((((buf)*4+(seg))<<13) + tid*8 + 4096)), 16, 0, 0); \
  } } while (0)

#define RD_AH(buf, mh, aa)                                                            \
  { _Pragma("unroll") for (int mm = 0; mm < 4; ++mm)                                  \
    _Pragma("unroll") for (int kk = 0; kk < 2; ++kk)                                  \
      aa[mm][kk] = *(const bf16x8*)(smem + (((buf)*4 + wr) << 14) + lrow*128          \
          + (mh)*8192 + mm*2048 + kxb[kk]); }

#define RD_BH(buf, nh, bf)                                                            \
  { _Pragma("unroll") for (int nn = 0; nn < 2; ++nn)                                  \
    _Pragma("unroll") for (int kk = 0; kk < 2; ++kk)                                  \
      bf[nn][kk] = *(const bf16x8*)(smem + (((buf)*4 + 2 + (wc>>1)) << 14)            \
          + ((wc&1)*64 + lrow)*128 + ((nh)*2+nn)*2048 + kxb[kk]); }

#define MMQ(mh, nh, aa, bf)                                                           \
  { __builtin_amdgcn_s_setprio(1);                                                    \
    _Pragma("unroll") for (int mm = 0; mm < 4; ++mm)                                  \
    _Pragma("unroll") for (int nn = 0; nn < 2; ++nn)                                  \
    _Pragma("unroll") for (int kk = 0; kk < 2; ++kk)                                  \
      acc[(mh)*4+mm][(nh)*2+nn] = __builtin_amdgcn_mfma_f32_16x16x32_bf16(            \
          aa[mm][kk], bf[nn][kk], acc[(mh)*4+mm][(nh)*2+nn], 0, 0, 0);                \
    __builtin_amdgcn_s_setprio(0); }

__global__ __launch_bounds__(512, 2) void gemm_kernel(const u16* __restrict__ A,
                                                      const u16* __restrict__ B,
                                                      float* __restrict__ C) {
    __shared__ u16 lds16[65536];                 // 128 KiB
    const char* smem = (const char*)lds16;

    const int tid  = threadIdx.x;
    const int lane = tid & 63, wid = tid >> 6;
    const int wr = wid >> 2, wc = wid & 3;       // 2M x 4N wave grid
    const int lrow = lane & 15;
    const int klo  = (lane >> 4) << 4;
    const int sx   = (lrow & 7) << 4;
    const int kxb[2] = { klo ^ sx, (64 + klo) ^ sx };

    // XCD-aware swizzle: 512 blocks, 512 % 8 == 0 -> bijective
    const int wg  = blockIdx.x;
    const int swz = (wg & 7) * 64 + (wg >> 3);
    const int bm = swz >> 4;                     // 32 row-tiles
    const int bn = swz & 15;                     // 16 col-tiles

    const int r0  = tid >> 3;
    const int sc4 = (tid & 7) ^ (r0 & 7);
    const u16* pA = A + (size_t)(bm * 256 + r0) * K2 + sc4 * 8;
    const u16* pB = B + (size_t)(bn * 256 + r0) * K2 + sc4 * 8;

    f32x4 acc[8][4];
#pragma unroll
    for (int m = 0; m < 8; ++m)
#pragma unroll
        for (int n = 0; n < 4; ++n) { f32x4 z = {0.f,0.f,0.f,0.f}; acc[m][n] = z; }
    bf16x8 a0[4][2], a1[4][2], bA[2][2], bB[2][2];

    // prologue: K0 all 4 segs (b0) + K1 A0,B0 (b1 segs 0,2); K1 A1,B1 at ph1
    STAGE(pA, 0, 0, 0, 0); STAGE(pA, 1, 0, 1, 0);
    STAGE(pB, 0, 0, 2, 0); STAGE(pB, 1, 0, 3, 0);
    STAGE(pA, 0, 1, 0, 1); STAGE(pB, 0, 1, 2, 1);
    VMCNT4();                                    // 12 out -> K0's 8 landed
    PHASE_BAR();

    for (int i = 0; i < GITERS; ++i) {
        const int kO = 2 * i + 1, kE2 = 2 * i + 2, kO2 = 2 * i + 3;
        // ph1: E=2i mh0; stage O.A1->b1.s1, O.B1->b1.s3
        RD_AH(0, 0, a0); RD_BH(0, 0, bA); RD_BH(0, 1, bB);
        STAGE(pA, 1, 1, 1, kO); STAGE(pB, 1, 1, 3, kO);
        MMQ(0, 0, a0, bA); MMQ(0, 1, a0, bB);
        PHASE_BAR();
        // ph2: E mh1; stage E'.A0->b0.s0, E'.B0->b0.s2; guard O landed
        RD_AH(0, 1, a1);
        STAGE(pA, 0, 0, 0, kE2); STAGE(pB, 0, 0, 2, kE2);
        MMQ(1, 0, a1, bA); MMQ(1, 1, a1, bB);
        VMCNT4();
        PHASE_BAR();
        // ph3: O mh0; stage E'.A1->b0.s1, E'.B1->b0.s3
        RD_AH(1, 0, a0); RD_BH(1, 0, bA); RD_BH(1, 1, bB);
        STAGE(pA, 1, 0, 1, kE2); STAGE(pB, 1, 0, 3, kE2);
        MMQ(0, 0, a0, bA); MMQ(0, 1, a0, bB);
        PHASE_BAR();
        // ph4: O mh1; stage O'.A0->b1.s0, O'.B0->b1.s2; guard E' landed
        RD_AH(1, 1, a1);
        STAGE(pA, 0, 1, 0, kO2); STAGE(pB, 0, 1, 2, kO2);
        MMQ(1, 0, a1, bA); MMQ(1, 1, a1, bB);
        VMCNT4();
        PHASE_BAR();
    }

    // tail: K-tile 68 (b0), staged during iter 33 ph2 (A0,B0) + ph3 (A1,B1)
    VMCNT0();
    PHASE_BAR();
    RD_AH(0, 0, a0); RD_AH(0, 1, a1); RD_BH(0, 0, bA); RD_BH(0, 1, bB);
    MMQ(0, 0, a0, bA); MMQ(1, 0, a1, bA); MMQ(0, 1, a0, bB); MMQ(1, 1, a1, bB);

    // epilogue: C/D layout col = lane&15, row = (lane>>4)*4 + reg
    const int crow0 = bm * 256 + wr * 128 + ((lane >> 4) << 2);
    const int ccol0 = bn * 256 + wc * 64 + (lane & 15);
#pragma unroll
    for (int m = 0; m < 8; ++m)
#pragma unroll
        for (int n = 0; n < 4; ++n)
#pragma unroll
            for (int rg = 0; rg < 4; ++rg)
                C[(size_t)(crow0 + m * 16 + rg) * DOUT + ccol0 + n * 16] = acc[m][n][rg];
}

// ---------------- launch ----------------

extern "C" void kernel_launch(void* const* d_in, const int* in_sizes, int n_in,
                              void* d_out, int out_size, void* d_ws, size_t ws_size,
                              hipStream_t stream) {
    const float* x         = (const float*)d_in[0];
    const float* W         = (const float*)d_in[1];
    const float* base_bias = (const float*)d_in[2];
    const float* lora_a    = (const float*)d_in[3];
    const float* lora_b    = (const float*)d_in[4];
    const float* bias_st   = (const float*)d_in[5];
    const int*   indices   = (const int*)d_in[6];
    float* out = (float*)d_out;

    u16* Abf  = (u16*)d_ws;                         // [T_TOK][K2] bf16
    u16* Bbf  = Abf + (size_t)T_TOK * K2;           // [DOUT][K2] bf16
    u16* Aabf = Bbf + (size_t)DOUT * K2;            // [256][DIN] bf16 lora_a

    pack_all<<<6144, 256, 0, stream>>>(x, W, lora_b, base_bias, bias_st, lora_a,
                                       Abf, Bbf, Aabf);
    zfill_kernel<<<512, 256, 0, stream>>>(Abf, Aabf, indices, Abf);
    gemm_kernel<<<512, 512, 0, stream>>>(Abf, Bbf, out);
    (void)in_sizes; (void)n_in; (void)out_size; (void)ws_size;
}